// Round 1
// baseline (238.691 us; speedup 1.0000x reference)
//
#include <hip/hip_runtime.h>
#include <math.h>

#define T_LEN 1024
#define EMB   512
#define NH    8
#define HD    64
#define PDIM  32
#define MDIM  4
#define FDIM  128   // PDIM*MDIM
#define TC    64    // chunk length
#define NC    16    // T_LEN/TC

// ---------------------------------------------------------------------------
// Kernel 1: qkv = x @ qkv_w^T + b, routed into q/k/v in [H][T][D] layout.
// C[1024,1536] tiled 64x64, 256 threads, 4x4 micro-tile, f32.
// ---------------------------------------------------------------------------
__global__ __launch_bounds__(256) void k_qkv_gemm(
    const float* __restrict__ X, const float* __restrict__ W,
    const float* __restrict__ bias,
    float* __restrict__ Qh, float* __restrict__ Kh, float* __restrict__ Vh)
{
    const int j0 = blockIdx.x * 64;   // column tile (0..1535)
    const int t0 = blockIdx.y * 64;   // row tile (0..1023)
    __shared__ float Xs[16][68];      // pad 68: 16B-aligned rows, spreads banks
    __shared__ float Ws[16][68];
    const int tid = threadIdx.x;
    const int tr = tid >> 4, tc = tid & 15;
    const int row = tid >> 2, kq = (tid & 3) << 2;
    float acc[4][4] = {};
    for (int k0 = 0; k0 < EMB; k0 += 16) {
        float4 xv = *reinterpret_cast<const float4*>(&X[(t0 + row) * EMB + k0 + kq]);
        Xs[kq+0][row] = xv.x; Xs[kq+1][row] = xv.y; Xs[kq+2][row] = xv.z; Xs[kq+3][row] = xv.w;
        float4 wv = *reinterpret_cast<const float4*>(&W[(j0 + row) * EMB + k0 + kq]);
        Ws[kq+0][row] = wv.x; Ws[kq+1][row] = wv.y; Ws[kq+2][row] = wv.z; Ws[kq+3][row] = wv.w;
        __syncthreads();
        #pragma unroll
        for (int kk = 0; kk < 16; ++kk) {
            float4 a4 = *reinterpret_cast<const float4*>(&Xs[kk][tr * 4]);
            float4 b4 = *reinterpret_cast<const float4*>(&Ws[kk][tc * 4]);
            float a[4] = {a4.x, a4.y, a4.z, a4.w};
            float b[4] = {b4.x, b4.y, b4.z, b4.w};
            #pragma unroll
            for (int i = 0; i < 4; ++i)
                #pragma unroll
                for (int j = 0; j < 4; ++j) acc[i][j] = fmaf(a[i], b[j], acc[i][j]);
        }
        __syncthreads();
    }
    const int which = j0 >> 9;            // 0:q 1:k 2:v (tile never crosses)
    const int h = (j0 & 511) >> 6;        // head
    float* dst = (which == 0) ? Qh : ((which == 1) ? Kh : Vh);
    #pragma unroll
    for (int i = 0; i < 4; ++i) {
        int t = t0 + tr * 4 + i;
        #pragma unroll
        for (int j = 0; j < 4; ++j) {
            int d = tc * 4 + j;
            dst[(h * T_LEN + t) * HD + d] = acc[i][j] + bias[j0 + d];
        }
    }
}

// ---------------------------------------------------------------------------
// Kernel 6: y = attn @ out_w^T + out_b, plain row-major output.
// ---------------------------------------------------------------------------
__global__ __launch_bounds__(256) void k_out_gemm(
    const float* __restrict__ Ain, const float* __restrict__ W,
    const float* __restrict__ bias, float* __restrict__ Y)
{
    const int j0 = blockIdx.x * 64;
    const int t0 = blockIdx.y * 64;
    __shared__ float Xs[16][68];
    __shared__ float Ws[16][68];
    const int tid = threadIdx.x;
    const int tr = tid >> 4, tc = tid & 15;
    const int row = tid >> 2, kq = (tid & 3) << 2;
    float acc[4][4] = {};
    for (int k0 = 0; k0 < EMB; k0 += 16) {
        float4 xv = *reinterpret_cast<const float4*>(&Ain[(t0 + row) * EMB + k0 + kq]);
        Xs[kq+0][row] = xv.x; Xs[kq+1][row] = xv.y; Xs[kq+2][row] = xv.z; Xs[kq+3][row] = xv.w;
        float4 wv = *reinterpret_cast<const float4*>(&W[(j0 + row) * EMB + k0 + kq]);
        Ws[kq+0][row] = wv.x; Ws[kq+1][row] = wv.y; Ws[kq+2][row] = wv.z; Ws[kq+3][row] = wv.w;
        __syncthreads();
        #pragma unroll
        for (int kk = 0; kk < 16; ++kk) {
            float4 a4 = *reinterpret_cast<const float4*>(&Xs[kk][tr * 4]);
            float4 b4 = *reinterpret_cast<const float4*>(&Ws[kk][tc * 4]);
            float a[4] = {a4.x, a4.y, a4.z, a4.w};
            float b[4] = {b4.x, b4.y, b4.z, b4.w};
            #pragma unroll
            for (int i = 0; i < 4; ++i)
                #pragma unroll
                for (int j = 0; j < 4; ++j) acc[i][j] = fmaf(a[i], b[j], acc[i][j]);
        }
        __syncthreads();
    }
    #pragma unroll
    for (int i = 0; i < 4; ++i) {
        int t = t0 + tr * 4 + i;
        #pragma unroll
        for (int j = 0; j < 4; ++j) {
            int cl = tc * 4 + j;
            Y[t * EMB + j0 + cl] = acc[i][j] + bias[j0 + cl];
        }
    }
}

// ---------------------------------------------------------------------------
// Kernel 2: features. One block per (h,t); wave0 -> q, wave1 -> k.
// zn = z/max(||z||,1e-12); poly_p = (zn.P_h[:,p])^2; prf_m = exp(clip(zn.om_m*sqrt2s - s))/2
// feat[f=p*4+m] = poly_p * prf_m
// ---------------------------------------------------------------------------
__global__ __launch_bounds__(128) void k_features(
    const float* __restrict__ Qh, const float* __restrict__ Kh,
    const float* __restrict__ poly_proj, const float* __restrict__ omega,
    float* __restrict__ QF, float* __restrict__ KF)
{
    const int ht = blockIdx.x;          // h*T + t
    const int h = ht >> 10;
    const int wid = threadIdx.x >> 6, lane = threadIdx.x & 63;
    const float* Z = (wid ? Kh : Qh) + ht * HD;
    float z = Z[lane];
    float ss = z * z;
    #pragma unroll
    for (int off = 32; off; off >>= 1) ss += __shfl_xor(ss, off, 64);
    const float inv = 1.0f / fmaxf(sqrtf(ss), 1e-12f);
    __shared__ float zs[2][64];
    __shared__ float poly[2][32];
    __shared__ float prf[2][4];
    zs[wid][lane] = z * inv;
    __syncthreads();
    const float S_NODE = (float)(1.0 / 2.000001);  // matches numpy astype(f32)
    const float SQRT2S = sqrtf(2.0f * S_NODE);
    if (lane < 32) {
        float a = 0.0f;
        for (int d = 0; d < 64; ++d)
            a = fmaf(zs[wid][d], poly_proj[(h * 64 + d) * 32 + lane], a);
        poly[wid][lane] = a * a;
    } else if (lane < 36) {
        const int m = lane - 32;
        float a = 0.0f;
        for (int d = 0; d < 64; ++d)
            a = fmaf(zs[wid][d], omega[(h * 64 + d) * 4 + m], a);
        float arg = fminf(fmaxf(fmaf(a, SQRT2S, -S_NODE), -20.0f), 20.0f);
        prf[wid][m] = expf(arg) * 0.5f;   // / sqrt(M=4)
    }
    __syncthreads();
    float* dst = wid ? KF : QF;
    #pragma unroll
    for (int r = 0; r < 2; ++r) {
        int f = lane * 2 + r;
        dst[ht * FDIM + f] = poly[wid][f >> 2] * prf[wid][f & 3];
    }
}

// ---------------------------------------------------------------------------
// Kernel 3: per-chunk state sums  S_c[f][d] = sum_t kf[t][f]*v[t][d], z_c[f].
// One block per (h, chunk): [128 x 64] output over K=64, 8x4 micro-tile.
// ---------------------------------------------------------------------------
__global__ __launch_bounds__(256) void k_chunk_kv(
    const float* __restrict__ KF, const float* __restrict__ Vh,
    float* __restrict__ Sch, float* __restrict__ zch)
{
    const int b = blockIdx.x;
    const int h = b >> 4, c = b & 15;
    const int t0 = c * TC;
    __shared__ float Ks[16][128];   // [kk][f]
    __shared__ float Vs[16][68];    // [kk][d]
    const int tid = threadIdx.x;
    const int tr = tid >> 4, tc_ = tid & 15;
    float acc[8][4] = {};
    float zsum = 0.0f;
    for (int tt0 = 0; tt0 < TC; tt0 += 16) {
        #pragma unroll
        for (int l = 0; l < 2; ++l) {
            int j = tid + l * 256;
            int kk = j >> 5, f4 = (j & 31) << 2;
            *reinterpret_cast<float4*>(&Ks[kk][f4]) =
                *reinterpret_cast<const float4*>(&KF[((h << 10) + t0 + tt0 + kk) * FDIM + f4]);
        }
        {
            int kk = tid >> 4, d4 = (tid & 15) << 2;
            *reinterpret_cast<float4*>(&Vs[kk][d4]) =
                *reinterpret_cast<const float4*>(&Vh[((h << 10) + t0 + tt0 + kk) * HD + d4]);
        }
        __syncthreads();
        #pragma unroll
        for (int kk = 0; kk < 16; ++kk) {
            float4 a0 = *reinterpret_cast<const float4*>(&Ks[kk][tr * 8]);
            float4 a1 = *reinterpret_cast<const float4*>(&Ks[kk][tr * 8 + 4]);
            float4 b4 = *reinterpret_cast<const float4*>(&Vs[kk][tc_ * 4]);
            float a[8] = {a0.x, a0.y, a0.z, a0.w, a1.x, a1.y, a1.z, a1.w};
            float bb[4] = {b4.x, b4.y, b4.z, b4.w};
            #pragma unroll
            for (int i = 0; i < 8; ++i)
                #pragma unroll
                for (int j = 0; j < 4; ++j) acc[i][j] = fmaf(a[i], bb[j], acc[i][j]);
        }
        if (tid < FDIM) {
            #pragma unroll
            for (int kk = 0; kk < 16; ++kk) zsum += Ks[kk][tid];
        }
        __syncthreads();
    }
    float* S = Sch + (size_t)(h * NC + c) * FDIM * HD;
    #pragma unroll
    for (int i = 0; i < 8; ++i) {
        int f = tr * 8 + i;
        *reinterpret_cast<float4*>(&S[f * HD + tc_ * 4]) =
            make_float4(acc[i][0], acc[i][1], acc[i][2], acc[i][3]);
    }
    if (tid < FDIM) zch[(h * NC + c) * FDIM + tid] = zsum;
}

// ---------------------------------------------------------------------------
// Kernel 4: exclusive prefix over chunks (per head). Tiny.
// ---------------------------------------------------------------------------
__global__ __launch_bounds__(256) void k_prefix(
    const float* __restrict__ Sch, const float* __restrict__ zch,
    float* __restrict__ Spre, float* __restrict__ zpre)
{
    const int h = blockIdx.x;
    const int tid = threadIdx.x;
    for (int e = tid; e < FDIM * HD; e += 256) {
        float run = 0.0f;
        for (int c = 0; c < NC; ++c) {
            size_t idx = (size_t)(h * NC + c) * FDIM * HD + e;
            Spre[idx] = run;
            run += Sch[idx];
        }
    }
    if (tid < FDIM) {
        float run = 0.0f;
        for (int c = 0; c < NC; ++c) {
            int idx = (h * NC + c) * FDIM + tid;
            zpre[idx] = run;
            run += zch[idx];
        }
    }
}

// ---------------------------------------------------------------------------
// Kernel 5: per-chunk output.
//   A[t][t'] = qf[t].kf[t'] (masked t'<=t), rowsum -> norm_intra
//   ctx = A@V + Qf@Spre ; norm = intra + qf.zpre ; attn = ctx/max(norm,1e-6)
// One block per (h, chunk), 256 threads.
// ---------------------------------------------------------------------------
__global__ __launch_bounds__(256) void k_attn_out(
    const float* __restrict__ QF, const float* __restrict__ KF,
    const float* __restrict__ Vh,
    const float* __restrict__ Spre, const float* __restrict__ zpre,
    float* __restrict__ attn)
{
    const int b = blockIdx.x;
    const int h = b >> 4, c = b & 15;
    const int t0 = c * TC;
    const int tid = threadIdx.x;
    const int tr = tid >> 4, tc_ = tid & 15;

    __shared__ float A[TC][68];
    __shared__ float Qs[16][68];   // [kk][t]  (transposed qf tile)
    __shared__ float Bs[16][68];   // kf tile in phase 1, V tile in phase 3
    __shared__ float Ss[16][68];   // Spre tile
    __shared__ float nrm[TC];
    __shared__ float zpre_s[FDIM];

    if (tid < FDIM) zpre_s[tid] = zpre[(h * NC + c) * FDIM + tid];

    float acc1[4][4] = {};  // A tile
    float acc2[4][4] = {};  // context
    float nint = 0.0f;      // inter-chunk norm contribution (threads tid<64)

    // ---- phase 1: loop over feature dim; build A and Qf@Spre together ----
    for (int f0 = 0; f0 < FDIM; f0 += 16) {
        {
            int tl = tid >> 2, fq = (tid & 3) << 2;
            float4 qv = *reinterpret_cast<const float4*>(
                &QF[((h << 10) + t0 + tl) * FDIM + f0 + fq]);
            Qs[fq+0][tl] = qv.x; Qs[fq+1][tl] = qv.y; Qs[fq+2][tl] = qv.z; Qs[fq+3][tl] = qv.w;
            float4 kv4 = *reinterpret_cast<const float4*>(
                &KF[((h << 10) + t0 + tl) * FDIM + f0 + fq]);
            Bs[fq+0][tl] = kv4.x; Bs[fq+1][tl] = kv4.y; Bs[fq+2][tl] = kv4.z; Bs[fq+3][tl] = kv4.w;
            int kkS = tid >> 4, d4 = (tid & 15) << 2;
            *reinterpret_cast<float4*>(&Ss[kkS][d4]) = *reinterpret_cast<const float4*>(
                &Spre[((size_t)(h * NC + c) * FDIM + f0 + kkS) * HD + d4]);
        }
        __syncthreads();
        #pragma unroll
        for (int kk = 0; kk < 16; ++kk) {
            float4 a4 = *reinterpret_cast<const float4*>(&Qs[kk][tr * 4]);
            float4 k4 = *reinterpret_cast<const float4*>(&Bs[kk][tc_ * 4]);
            float4 s4 = *reinterpret_cast<const float4*>(&Ss[kk][tc_ * 4]);
            float a[4] = {a4.x, a4.y, a4.z, a4.w};
            float bk[4] = {k4.x, k4.y, k4.z, k4.w};
            float bs[4] = {s4.x, s4.y, s4.z, s4.w};
            #pragma unroll
            for (int i = 0; i < 4; ++i)
                #pragma unroll
                for (int j = 0; j < 4; ++j) {
                    acc1[i][j] = fmaf(a[i], bk[j], acc1[i][j]);
                    acc2[i][j] = fmaf(a[i], bs[j], acc2[i][j]);
                }
        }
        if (tid < TC) {
            #pragma unroll
            for (int kk = 0; kk < 16; ++kk)
                nint = fmaf(Qs[kk][tid], zpre_s[f0 + kk], nint);
        }
        __syncthreads();
    }

    // ---- phase 2: mask, row-sums (norm_intra), write A to LDS ----
    float rs[4];
    #pragma unroll
    for (int i = 0; i < 4; ++i) {
        int tl = tr * 4 + i;
        rs[i] = 0.0f;
        #pragma unroll
        for (int j = 0; j < 4; ++j) {
            int tp = tc_ * 4 + j;
            float vA = (tp <= tl) ? acc1[i][j] : 0.0f;
            acc1[i][j] = vA;
            rs[i] += vA;
        }
        #pragma unroll
        for (int off = 1; off < 16; off <<= 1) rs[i] += __shfl_xor(rs[i], off, 64);
    }
    if (tc_ == 0) {
        #pragma unroll
        for (int i = 0; i < 4; ++i) nrm[tr * 4 + i] = rs[i];
    }
    #pragma unroll
    for (int i = 0; i < 4; ++i)
        *reinterpret_cast<float4*>(&A[tr * 4 + i][tc_ * 4]) =
            make_float4(acc1[i][0], acc1[i][1], acc1[i][2], acc1[i][3]);
    __syncthreads();

    // ---- phase 3: intra-chunk context += A_masked @ V ----
    for (int kk0 = 0; kk0 < TC; kk0 += 16) {
        {
            int kkV = tid >> 4, d4 = (tid & 15) << 2;
            *reinterpret_cast<float4*>(&Bs[kkV][d4]) = *reinterpret_cast<const float4*>(
                &Vh[((h << 10) + t0 + kk0 + kkV) * HD + d4]);
        }
        __syncthreads();
        #pragma unroll
        for (int kk = 0; kk < 16; ++kk) {
            float4 b4 = *reinterpret_cast<const float4*>(&Bs[kk][tc_ * 4]);
            float bb[4] = {b4.x, b4.y, b4.z, b4.w};
            #pragma unroll
            for (int i = 0; i < 4; ++i) {
                float a = A[tr * 4 + i][kk0 + kk];
                #pragma unroll
                for (int j = 0; j < 4; ++j) acc2[i][j] = fmaf(a, bb[j], acc2[i][j]);
            }
        }
        __syncthreads();
    }

    if (tid < TC) nrm[tid] = fmaxf(nrm[tid] + nint, 1e-6f);
    __syncthreads();

    #pragma unroll
    for (int i = 0; i < 4; ++i) {
        int tg = t0 + tr * 4 + i;
        float n = nrm[tr * 4 + i];
        float4 o = make_float4(acc2[i][0] / n, acc2[i][1] / n,
                               acc2[i][2] / n, acc2[i][3] / n);
        *reinterpret_cast<float4*>(&attn[tg * EMB + h * HD + tc_ * 4]) = o;
    }
}

// ---------------------------------------------------------------------------
extern "C" void kernel_launch(void* const* d_in, const int* in_sizes, int n_in,
                              void* d_out, int out_size, void* d_ws, size_t ws_size,
                              hipStream_t stream) {
    const float* x         = (const float*)d_in[0];
    const float* qkv_w     = (const float*)d_in[1];
    const float* qkv_b     = (const float*)d_in[2];
    const float* out_w     = (const float*)d_in[3];
    const float* out_b     = (const float*)d_in[4];
    const float* omega     = (const float*)d_in[5];
    const float* poly_proj = (const float*)d_in[6];
    float* out = (float*)d_out;

    float* ws   = (float*)d_ws;
    float* q    = ws;                           // [H][T][D]   524288
    float* k    = q    + NH * T_LEN * HD;       // 524288
    float* v    = k    + NH * T_LEN * HD;       // 524288
    float* qf   = v    + NH * T_LEN * HD;       // [H][T][F]  1048576
    float* kf   = qf   + NH * T_LEN * FDIM;     // 1048576
    float* Sch  = kf   + NH * T_LEN * FDIM;     // [H][NC][F][D] 1048576
    float* Spre = Sch  + NH * NC * FDIM * HD;   // 1048576
    float* zch  = Spre + NH * NC * FDIM * HD;   // 16384
    float* zpre = zch  + NH * NC * FDIM;        // 16384
    float* attn = zpre + NH * NC * FDIM;        // [T][EMB] 524288

    k_qkv_gemm<<<dim3(24, 16), 256, 0, stream>>>(x, qkv_w, qkv_b, q, k, v);
    k_features<<<NH * T_LEN, 128, 0, stream>>>(q, k, poly_proj, omega, qf, kf);
    k_chunk_kv<<<NH * NC, 256, 0, stream>>>(kf, v, Sch, zch);
    k_prefix<<<NH, 256, 0, stream>>>(Sch, zch, Spre, zpre);
    k_attn_out<<<NH * NC, 256, 0, stream>>>(qf, kf, v, Spre, zpre, attn);
    k_out_gemm<<<dim3(8, 16), 256, 0, stream>>>(attn, out_w, out_b, out);
}

// Round 2
// 180.026 us; speedup vs baseline: 1.3259x; 1.3259x over previous
//
#include <hip/hip_runtime.h>
#include <math.h>

#define T_LEN 1024
#define EMB   512
#define NH    8
#define HD    64
#define PDIM  32
#define MDIM  4
#define FDIM  128   // PDIM*MDIM
#define TC    64    // chunk length
#define NC    16    // T_LEN/TC

// ---------------------------------------------------------------------------
// Kernel 1: qkv = x @ qkv_w^T + b, routed into q/k/v in [H][T][D] layout.
// C[1024,1536] tiled 64x64, 256 threads, 4x4 micro-tile, f32.
// ---------------------------------------------------------------------------
__global__ __launch_bounds__(256) void k_qkv_gemm(
    const float* __restrict__ X, const float* __restrict__ W,
    const float* __restrict__ bias,
    float* __restrict__ Qh, float* __restrict__ Kh, float* __restrict__ Vh)
{
    const int j0 = blockIdx.x * 64;   // column tile (0..1535)
    const int t0 = blockIdx.y * 64;   // row tile (0..1023)
    __shared__ float Xs[16][68];      // pad 68: 16B-aligned rows, spreads banks
    __shared__ float Ws[16][68];
    const int tid = threadIdx.x;
    const int tr = tid >> 4, tc = tid & 15;
    const int row = tid >> 2, kq = (tid & 3) << 2;
    float acc[4][4] = {};
    for (int k0 = 0; k0 < EMB; k0 += 16) {
        float4 xv = *reinterpret_cast<const float4*>(&X[(t0 + row) * EMB + k0 + kq]);
        Xs[kq+0][row] = xv.x; Xs[kq+1][row] = xv.y; Xs[kq+2][row] = xv.z; Xs[kq+3][row] = xv.w;
        float4 wv = *reinterpret_cast<const float4*>(&W[(j0 + row) * EMB + k0 + kq]);
        Ws[kq+0][row] = wv.x; Ws[kq+1][row] = wv.y; Ws[kq+2][row] = wv.z; Ws[kq+3][row] = wv.w;
        __syncthreads();
        #pragma unroll
        for (int kk = 0; kk < 16; ++kk) {
            float4 a4 = *reinterpret_cast<const float4*>(&Xs[kk][tr * 4]);
            float4 b4 = *reinterpret_cast<const float4*>(&Ws[kk][tc * 4]);
            float a[4] = {a4.x, a4.y, a4.z, a4.w};
            float b[4] = {b4.x, b4.y, b4.z, b4.w};
            #pragma unroll
            for (int i = 0; i < 4; ++i)
                #pragma unroll
                for (int j = 0; j < 4; ++j) acc[i][j] = fmaf(a[i], b[j], acc[i][j]);
        }
        __syncthreads();
    }
    const int which = j0 >> 9;            // 0:q 1:k 2:v (tile never crosses)
    const int h = (j0 & 511) >> 6;        // head
    float* dst = (which == 0) ? Qh : ((which == 1) ? Kh : Vh);
    #pragma unroll
    for (int i = 0; i < 4; ++i) {
        int t = t0 + tr * 4 + i;
        #pragma unroll
        for (int j = 0; j < 4; ++j) {
            int d = tc * 4 + j;
            dst[(h * T_LEN + t) * HD + d] = acc[i][j] + bias[j0 + d];
        }
    }
}

// ---------------------------------------------------------------------------
// Kernel 6: y = attn @ out_w^T + out_b, plain row-major output.
// ---------------------------------------------------------------------------
__global__ __launch_bounds__(256) void k_out_gemm(
    const float* __restrict__ Ain, const float* __restrict__ W,
    const float* __restrict__ bias, float* __restrict__ Y)
{
    const int j0 = blockIdx.x * 64;
    const int t0 = blockIdx.y * 64;
    __shared__ float Xs[16][68];
    __shared__ float Ws[16][68];
    const int tid = threadIdx.x;
    const int tr = tid >> 4, tc = tid & 15;
    const int row = tid >> 2, kq = (tid & 3) << 2;
    float acc[4][4] = {};
    for (int k0 = 0; k0 < EMB; k0 += 16) {
        float4 xv = *reinterpret_cast<const float4*>(&Ain[(t0 + row) * EMB + k0 + kq]);
        Xs[kq+0][row] = xv.x; Xs[kq+1][row] = xv.y; Xs[kq+2][row] = xv.z; Xs[kq+3][row] = xv.w;
        float4 wv = *reinterpret_cast<const float4*>(&W[(j0 + row) * EMB + k0 + kq]);
        Ws[kq+0][row] = wv.x; Ws[kq+1][row] = wv.y; Ws[kq+2][row] = wv.z; Ws[kq+3][row] = wv.w;
        __syncthreads();
        #pragma unroll
        for (int kk = 0; kk < 16; ++kk) {
            float4 a4 = *reinterpret_cast<const float4*>(&Xs[kk][tr * 4]);
            float4 b4 = *reinterpret_cast<const float4*>(&Ws[kk][tc * 4]);
            float a[4] = {a4.x, a4.y, a4.z, a4.w};
            float b[4] = {b4.x, b4.y, b4.z, b4.w};
            #pragma unroll
            for (int i = 0; i < 4; ++i)
                #pragma unroll
                for (int j = 0; j < 4; ++j) acc[i][j] = fmaf(a[i], b[j], acc[i][j]);
        }
        __syncthreads();
    }
    #pragma unroll
    for (int i = 0; i < 4; ++i) {
        int t = t0 + tr * 4 + i;
        #pragma unroll
        for (int j = 0; j < 4; ++j) {
            int cl = tc * 4 + j;
            Y[t * EMB + j0 + cl] = acc[i][j] + bias[j0 + cl];
        }
    }
}

// ---------------------------------------------------------------------------
// Kernel 2: features. One block per (h,t); wave0 -> q, wave1 -> k.
// ---------------------------------------------------------------------------
__global__ __launch_bounds__(128) void k_features(
    const float* __restrict__ Qh, const float* __restrict__ Kh,
    const float* __restrict__ poly_proj, const float* __restrict__ omega,
    float* __restrict__ QF, float* __restrict__ KF)
{
    const int ht = blockIdx.x;          // h*T + t
    const int h = ht >> 10;
    const int wid = threadIdx.x >> 6, lane = threadIdx.x & 63;
    const float* Z = (wid ? Kh : Qh) + ht * HD;
    float z = Z[lane];
    float ss = z * z;
    #pragma unroll
    for (int off = 32; off; off >>= 1) ss += __shfl_xor(ss, off, 64);
    const float inv = 1.0f / fmaxf(sqrtf(ss), 1e-12f);
    __shared__ float zs[2][64];
    __shared__ float poly[2][32];
    __shared__ float prf[2][4];
    zs[wid][lane] = z * inv;
    __syncthreads();
    const float S_NODE = (float)(1.0 / 2.000001);  // matches numpy astype(f32)
    const float SQRT2S = sqrtf(2.0f * S_NODE);
    if (lane < 32) {
        float a = 0.0f;
        for (int d = 0; d < 64; ++d)
            a = fmaf(zs[wid][d], poly_proj[(h * 64 + d) * 32 + lane], a);
        poly[wid][lane] = a * a;
    } else if (lane < 36) {
        const int m = lane - 32;
        float a = 0.0f;
        for (int d = 0; d < 64; ++d)
            a = fmaf(zs[wid][d], omega[(h * 64 + d) * 4 + m], a);
        float arg = fminf(fmaxf(fmaf(a, SQRT2S, -S_NODE), -20.0f), 20.0f);
        prf[wid][m] = expf(arg) * 0.5f;   // / sqrt(M=4)
    }
    __syncthreads();
    float* dst = wid ? KF : QF;
    #pragma unroll
    for (int r = 0; r < 2; ++r) {
        int f = lane * 2 + r;
        dst[ht * FDIM + f] = poly[wid][f >> 2] * prf[wid][f & 3];
    }
}

// ---------------------------------------------------------------------------
// Kernel 3: per-chunk state sums  S_c[f][d] = sum_t kf[t][f]*v[t][d], z_c[f].
// ---------------------------------------------------------------------------
__global__ __launch_bounds__(256) void k_chunk_kv(
    const float* __restrict__ KF, const float* __restrict__ Vh,
    float* __restrict__ Sch, float* __restrict__ zch)
{
    const int b = blockIdx.x;
    const int h = b >> 4, c = b & 15;
    const int t0 = c * TC;
    __shared__ float Ks[16][128];   // [kk][f]
    __shared__ float Vs[16][68];    // [kk][d]
    const int tid = threadIdx.x;
    const int tr = tid >> 4, tc_ = tid & 15;
    float acc[8][4] = {};
    float zsum = 0.0f;
    for (int tt0 = 0; tt0 < TC; tt0 += 16) {
        #pragma unroll
        for (int l = 0; l < 2; ++l) {
            int j = tid + l * 256;
            int kk = j >> 5, f4 = (j & 31) << 2;
            *reinterpret_cast<float4*>(&Ks[kk][f4]) =
                *reinterpret_cast<const float4*>(&KF[((h << 10) + t0 + tt0 + kk) * FDIM + f4]);
        }
        {
            int kk = tid >> 4, d4 = (tid & 15) << 2;
            *reinterpret_cast<float4*>(&Vs[kk][d4]) =
                *reinterpret_cast<const float4*>(&Vh[((h << 10) + t0 + tt0 + kk) * HD + d4]);
        }
        __syncthreads();
        #pragma unroll
        for (int kk = 0; kk < 16; ++kk) {
            float4 a0 = *reinterpret_cast<const float4*>(&Ks[kk][tr * 8]);
            float4 a1 = *reinterpret_cast<const float4*>(&Ks[kk][tr * 8 + 4]);
            float4 b4 = *reinterpret_cast<const float4*>(&Vs[kk][tc_ * 4]);
            float a[8] = {a0.x, a0.y, a0.z, a0.w, a1.x, a1.y, a1.z, a1.w};
            float bb[4] = {b4.x, b4.y, b4.z, b4.w};
            #pragma unroll
            for (int i = 0; i < 8; ++i)
                #pragma unroll
                for (int j = 0; j < 4; ++j) acc[i][j] = fmaf(a[i], bb[j], acc[i][j]);
        }
        if (tid < FDIM) {
            #pragma unroll
            for (int kk = 0; kk < 16; ++kk) zsum += Ks[kk][tid];
        }
        __syncthreads();
    }
    float* S = Sch + (size_t)(h * NC + c) * FDIM * HD;
    #pragma unroll
    for (int i = 0; i < 8; ++i) {
        int f = tr * 8 + i;
        *reinterpret_cast<float4*>(&S[f * HD + tc_ * 4]) =
            make_float4(acc[i][0], acc[i][1], acc[i][2], acc[i][3]);
    }
    if (tid < FDIM) zch[(h * NC + c) * FDIM + tid] = zsum;
}

// ---------------------------------------------------------------------------
// Kernel 4: exclusive prefix over chunks. PARALLELIZED:
// one thread per (h, element) chain; 16 values register-resident.
// grid = NH*32 blocks x 256 threads = 65536 chains.
// ---------------------------------------------------------------------------
__global__ __launch_bounds__(256) void k_prefix(
    const float* __restrict__ Sch, const float* __restrict__ zch,
    float* __restrict__ Spre, float* __restrict__ zpre)
{
    const int h = blockIdx.x >> 5;
    const int e = ((blockIdx.x & 31) << 8) + threadIdx.x;   // 0..8191
    const size_t base = (size_t)h * NC * FDIM * HD + e;
    float vals[NC];
    #pragma unroll
    for (int c = 0; c < NC; ++c)
        vals[c] = Sch[base + (size_t)c * FDIM * HD];
    float run = 0.0f;
    #pragma unroll
    for (int c = 0; c < NC; ++c) {
        Spre[base + (size_t)c * FDIM * HD] = run;
        run += vals[c];
    }
    if ((blockIdx.x & 31) == 0 && threadIdx.x < FDIM) {
        const int zb = h * NC * FDIM + threadIdx.x;
        float zv[NC];
        #pragma unroll
        for (int c = 0; c < NC; ++c) zv[c] = zch[zb + c * FDIM];
        float zr = 0.0f;
        #pragma unroll
        for (int c = 0; c < NC; ++c) {
            zpre[zb + c * FDIM] = zr;
            zr += zv[c];
        }
    }
}

// ---------------------------------------------------------------------------
// Kernel 5: per-chunk output.
// ---------------------------------------------------------------------------
__global__ __launch_bounds__(256) void k_attn_out(
    const float* __restrict__ QF, const float* __restrict__ KF,
    const float* __restrict__ Vh,
    const float* __restrict__ Spre, const float* __restrict__ zpre,
    float* __restrict__ attn)
{
    const int b = blockIdx.x;
    const int h = b >> 4, c = b & 15;
    const int t0 = c * TC;
    const int tid = threadIdx.x;
    const int tr = tid >> 4, tc_ = tid & 15;

    __shared__ float A[TC][68];
    __shared__ float Qs[16][68];   // [kk][t]  (transposed qf tile)
    __shared__ float Bs[16][68];   // kf tile in phase 1, V tile in phase 3
    __shared__ float Ss[16][68];   // Spre tile
    __shared__ float nrm[TC];
    __shared__ float zpre_s[FDIM];

    if (tid < FDIM) zpre_s[tid] = zpre[(h * NC + c) * FDIM + tid];

    float acc1[4][4] = {};  // A tile
    float acc2[4][4] = {};  // context
    float nint = 0.0f;      // inter-chunk norm contribution (threads tid<64)

    // ---- phase 1: loop over feature dim; build A and Qf@Spre together ----
    for (int f0 = 0; f0 < FDIM; f0 += 16) {
        {
            int tl = tid >> 2, fq = (tid & 3) << 2;
            float4 qv = *reinterpret_cast<const float4*>(
                &QF[((h << 10) + t0 + tl) * FDIM + f0 + fq]);
            Qs[fq+0][tl] = qv.x; Qs[fq+1][tl] = qv.y; Qs[fq+2][tl] = qv.z; Qs[fq+3][tl] = qv.w;
            float4 kv4 = *reinterpret_cast<const float4*>(
                &KF[((h << 10) + t0 + tl) * FDIM + f0 + fq]);
            Bs[fq+0][tl] = kv4.x; Bs[fq+1][tl] = kv4.y; Bs[fq+2][tl] = kv4.z; Bs[fq+3][tl] = kv4.w;
            int kkS = tid >> 4, d4 = (tid & 15) << 2;
            *reinterpret_cast<float4*>(&Ss[kkS][d4]) = *reinterpret_cast<const float4*>(
                &Spre[((size_t)(h * NC + c) * FDIM + f0 + kkS) * HD + d4]);
        }
        __syncthreads();
        #pragma unroll
        for (int kk = 0; kk < 16; ++kk) {
            float4 a4 = *reinterpret_cast<const float4*>(&Qs[kk][tr * 4]);
            float4 k4 = *reinterpret_cast<const float4*>(&Bs[kk][tc_ * 4]);
            float4 s4 = *reinterpret_cast<const float4*>(&Ss[kk][tc_ * 4]);
            float a[4] = {a4.x, a4.y, a4.z, a4.w};
            float bk[4] = {k4.x, k4.y, k4.z, k4.w};
            float bs[4] = {s4.x, s4.y, s4.z, s4.w};
            #pragma unroll
            for (int i = 0; i < 4; ++i)
                #pragma unroll
                for (int j = 0; j < 4; ++j) {
                    acc1[i][j] = fmaf(a[i], bk[j], acc1[i][j]);
                    acc2[i][j] = fmaf(a[i], bs[j], acc2[i][j]);
                }
        }
        if (tid < TC) {
            #pragma unroll
            for (int kk = 0; kk < 16; ++kk)
                nint = fmaf(Qs[kk][tid], zpre_s[f0 + kk], nint);
        }
        __syncthreads();
    }

    // ---- phase 2: mask, row-sums (norm_intra), write A to LDS ----
    float rs[4];
    #pragma unroll
    for (int i = 0; i < 4; ++i) {
        int tl = tr * 4 + i;
        rs[i] = 0.0f;
        #pragma unroll
        for (int j = 0; j < 4; ++j) {
            int tp = tc_ * 4 + j;
            float vA = (tp <= tl) ? acc1[i][j] : 0.0f;
            acc1[i][j] = vA;
            rs[i] += vA;
        }
        #pragma unroll
        for (int off = 1; off < 16; off <<= 1) rs[i] += __shfl_xor(rs[i], off, 64);
    }
    if (tc_ == 0) {
        #pragma unroll
        for (int i = 0; i < 4; ++i) nrm[tr * 4 + i] = rs[i];
    }
    #pragma unroll
    for (int i = 0; i < 4; ++i)
        *reinterpret_cast<float4*>(&A[tr * 4 + i][tc_ * 4]) =
            make_float4(acc1[i][0], acc1[i][1], acc1[i][2], acc1[i][3]);
    __syncthreads();

    // ---- phase 3: intra-chunk context += A_masked @ V ----
    for (int kk0 = 0; kk0 < TC; kk0 += 16) {
        {
            int kkV = tid >> 4, d4 = (tid & 15) << 2;
            *reinterpret_cast<float4*>(&Bs[kkV][d4]) = *reinterpret_cast<const float4*>(
                &Vh[((h << 10) + t0 + kk0 + kkV) * HD + d4]);
        }
        __syncthreads();
        #pragma unroll
        for (int kk = 0; kk < 16; ++kk) {
            float4 b4 = *reinterpret_cast<const float4*>(&Bs[kk][tc_ * 4]);
            float bb[4] = {b4.x, b4.y, b4.z, b4.w};
            #pragma unroll
            for (int i = 0; i < 4; ++i) {
                float a = A[tr * 4 + i][kk0 + kk];
                #pragma unroll
                for (int j = 0; j < 4; ++j) acc2[i][j] = fmaf(a, bb[j], acc2[i][j]);
            }
        }
        __syncthreads();
    }

    if (tid < TC) nrm[tid] = fmaxf(nrm[tid] + nint, 1e-6f);
    __syncthreads();

    #pragma unroll
    for (int i = 0; i < 4; ++i) {
        int tg = t0 + tr * 4 + i;
        float n = nrm[tr * 4 + i];
        float4 o = make_float4(acc2[i][0] / n, acc2[i][1] / n,
                               acc2[i][2] / n, acc2[i][3] / n);
        *reinterpret_cast<float4*>(&attn[tg * EMB + h * HD + tc_ * 4]) = o;
    }
}

// ---------------------------------------------------------------------------
extern "C" void kernel_launch(void* const* d_in, const int* in_sizes, int n_in,
                              void* d_out, int out_size, void* d_ws, size_t ws_size,
                              hipStream_t stream) {
    const float* x         = (const float*)d_in[0];
    const float* qkv_w     = (const float*)d_in[1];
    const float* qkv_b     = (const float*)d_in[2];
    const float* out_w     = (const float*)d_in[3];
    const float* out_b     = (const float*)d_in[4];
    const float* omega     = (const float*)d_in[5];
    const float* poly_proj = (const float*)d_in[6];
    float* out = (float*)d_out;

    float* ws   = (float*)d_ws;
    float* q    = ws;                           // [H][T][D]   524288
    float* k    = q    + NH * T_LEN * HD;       // 524288
    float* v    = k    + NH * T_LEN * HD;       // 524288
    float* qf   = v    + NH * T_LEN * HD;       // [H][T][F]  1048576
    float* kf   = qf   + NH * T_LEN * FDIM;     // 1048576
    float* Sch  = kf   + NH * T_LEN * FDIM;     // [H][NC][F][D] 1048576
    float* Spre = Sch  + NH * NC * FDIM * HD;   // 1048576
    float* zch  = Spre + NH * NC * FDIM * HD;   // 16384
    float* zpre = zch  + NH * NC * FDIM;        // 16384
    float* attn = zpre + NH * NC * FDIM;        // [T][EMB] 524288

    k_qkv_gemm<<<dim3(24, 16), 256, 0, stream>>>(x, qkv_w, qkv_b, q, k, v);
    k_features<<<NH * T_LEN, 128, 0, stream>>>(q, k, poly_proj, omega, qf, kf);
    k_chunk_kv<<<NH * NC, 256, 0, stream>>>(kf, v, Sch, zch);
    k_prefix<<<NH * 32, 256, 0, stream>>>(Sch, zch, Spre, zpre);
    k_attn_out<<<NH * NC, 256, 0, stream>>>(qf, kf, v, Spre, zpre, attn);
    k_out_gemm<<<dim3(8, 16), 256, 0, stream>>>(attn, out_w, out_b, out);
}

// Round 4
// 161.251 us; speedup vs baseline: 1.4802x; 1.1164x over previous
//
#include <hip/hip_runtime.h>
#include <math.h>

#define T_LEN 1024
#define EMB   512
#define NH    8
#define HD    64
#define PDIM  32
#define MDIM  4
#define FDIM  128   // PDIM*MDIM
#define TC    64    // chunk length
#define NC    16    // T_LEN/TC

typedef __attribute__((ext_vector_type(8))) short bf16x8;
typedef __attribute__((ext_vector_type(4))) float f32x4;

__device__ __forceinline__ unsigned short f2bf(float f) {
    unsigned u = __float_as_uint(f);
    unsigned r = u + 0x7fffu + ((u >> 16) & 1u);   // RNE
    return (unsigned short)(r >> 16);
}
__device__ __forceinline__ float bf2f(unsigned short h) {
    return __uint_as_float(((unsigned)h) << 16);
}

// ---------------------------------------------------------------------------
// Kernel 0: split f32 -> bf16 hi/lo for x, qkv_w, out_w.
// ---------------------------------------------------------------------------
__global__ __launch_bounds__(256) void k_cvt(
    const float* __restrict__ X, const float* __restrict__ Wq,
    const float* __restrict__ Wo,
    unsigned short* __restrict__ Xhi, unsigned short* __restrict__ Xlo,
    unsigned short* __restrict__ Whi, unsigned short* __restrict__ Wlo,
    unsigned short* __restrict__ Ohi, unsigned short* __restrict__ Olo)
{
    int i = (blockIdx.x * 256 + threadIdx.x) * 4;
    const float* src; unsigned short *dh, *dl; int off;
    if (i < 524288)       { src = X;  dh = Xhi; dl = Xlo; off = i; }
    else if (i < 1310720) { src = Wq; dh = Whi; dl = Wlo; off = i - 524288; }
    else                  { src = Wo; dh = Ohi; dl = Olo; off = i - 1310720; }
    float4 v = *reinterpret_cast<const float4*>(&src[off]);
    ushort4 h4, l4;
    h4.x = f2bf(v.x); l4.x = f2bf(v.x - bf2f(h4.x));
    h4.y = f2bf(v.y); l4.y = f2bf(v.y - bf2f(h4.y));
    h4.z = f2bf(v.z); l4.z = f2bf(v.z - bf2f(h4.z));
    h4.w = f2bf(v.w); l4.w = f2bf(v.w - bf2f(h4.w));
    *reinterpret_cast<ushort4*>(&dh[off]) = h4;
    *reinterpret_cast<ushort4*>(&dl[off]) = l4;
}

// ---------------------------------------------------------------------------
// Kernel 1: qkv = x @ qkv_w^T + b via split-bf16 MFMA (hi*hi + hi*lo + lo*hi),
// routed into q/k/v [H][T][D] f32. 64x64 tile, 4 waves, 2x2 16x16x32 frags.
// ---------------------------------------------------------------------------
__global__ __launch_bounds__(256) void k_qkv_mfma(
    const unsigned short* __restrict__ Ahi, const unsigned short* __restrict__ Alo,
    const unsigned short* __restrict__ Bhi, const unsigned short* __restrict__ Blo,
    const float* __restrict__ bias,
    float* __restrict__ Qh, float* __restrict__ Kh, float* __restrict__ Vh)
{
    const int j0 = blockIdx.x * 64;   // column tile (N=1536)
    const int t0 = blockIdx.y * 64;   // row tile (M=1024)
    __shared__ __align__(16) short As[64][72];
    __shared__ __align__(16) short Bs[64][72];
    const int tid = threadIdx.x;
    const int lane = tid & 63, wid = tid >> 6;
    const int wrow = (wid >> 1) * 32, wcol = (wid & 1) * 32;
    const int srow = tid >> 3, sseg = (tid & 7) * 8;   // rows srow, srow+32
    f32x4 acc[2][2];
    #pragma unroll
    for (int i = 0; i < 2; ++i)
        #pragma unroll
        for (int j = 0; j < 2; ++j) acc[i][j] = (f32x4){0.f, 0.f, 0.f, 0.f};

    #pragma unroll 1
    for (int pass = 0; pass < 3; ++pass) {
        const unsigned short* Asrc = (pass < 2) ? Ahi : Alo;
        const unsigned short* Bsrc = (pass == 1) ? Blo : Bhi;
        for (int k0 = 0; k0 < 512; k0 += 64) {
            *reinterpret_cast<int4*>(&As[srow][sseg]) =
                *reinterpret_cast<const int4*>(&Asrc[(t0 + srow) * 512 + k0 + sseg]);
            *reinterpret_cast<int4*>(&As[srow + 32][sseg]) =
                *reinterpret_cast<const int4*>(&Asrc[(t0 + srow + 32) * 512 + k0 + sseg]);
            *reinterpret_cast<int4*>(&Bs[srow][sseg]) =
                *reinterpret_cast<const int4*>(&Bsrc[(j0 + srow) * 512 + k0 + sseg]);
            *reinterpret_cast<int4*>(&Bs[srow + 32][sseg]) =
                *reinterpret_cast<const int4*>(&Bsrc[(j0 + srow + 32) * 512 + k0 + sseg]);
            __syncthreads();
            #pragma unroll
            for (int kh = 0; kh < 2; ++kh) {
                const int kb = kh * 32 + (lane >> 4) * 8;
                bf16x8 a0 = *reinterpret_cast<const bf16x8*>(&As[wrow + (lane & 15)][kb]);
                bf16x8 a1 = *reinterpret_cast<const bf16x8*>(&As[wrow + 16 + (lane & 15)][kb]);
                bf16x8 b0 = *reinterpret_cast<const bf16x8*>(&Bs[wcol + (lane & 15)][kb]);
                bf16x8 b1 = *reinterpret_cast<const bf16x8*>(&Bs[wcol + 16 + (lane & 15)][kb]);
                acc[0][0] = __builtin_amdgcn_mfma_f32_16x16x32_bf16(a0, b0, acc[0][0], 0, 0, 0);
                acc[0][1] = __builtin_amdgcn_mfma_f32_16x16x32_bf16(a0, b1, acc[0][1], 0, 0, 0);
                acc[1][0] = __builtin_amdgcn_mfma_f32_16x16x32_bf16(a1, b0, acc[1][0], 0, 0, 0);
                acc[1][1] = __builtin_amdgcn_mfma_f32_16x16x32_bf16(a1, b1, acc[1][1], 0, 0, 0);
            }
            __syncthreads();
        }
    }
    const int which = j0 >> 9;
    const int h = (j0 & 511) >> 6;
    float* dst = (which == 0) ? Qh : ((which == 1) ? Kh : Vh);
    #pragma unroll
    for (int i = 0; i < 2; ++i)
        #pragma unroll
        for (int j = 0; j < 2; ++j)
            #pragma unroll
            for (int r = 0; r < 4; ++r) {
                int row = wrow + i * 16 + (lane >> 4) * 4 + r;
                int col = wcol + j * 16 + (lane & 15);
                int t = t0 + row, n = j0 + col;
                dst[(h * T_LEN + t) * HD + col] = acc[i][j][r] + bias[n];
            }
}

// ---------------------------------------------------------------------------
// Kernel 6: y = attn @ out_w^T + out_b via split-bf16 MFMA. N=512, K=512.
// ---------------------------------------------------------------------------
__global__ __launch_bounds__(256) void k_out_mfma(
    const unsigned short* __restrict__ Ahi, const unsigned short* __restrict__ Alo,
    const unsigned short* __restrict__ Bhi, const unsigned short* __restrict__ Blo,
    const float* __restrict__ bias, float* __restrict__ Y)
{
    const int j0 = blockIdx.x * 64;
    const int t0 = blockIdx.y * 64;
    __shared__ __align__(16) short As[64][72];
    __shared__ __align__(16) short Bs[64][72];
    const int tid = threadIdx.x;
    const int lane = tid & 63, wid = tid >> 6;
    const int wrow = (wid >> 1) * 32, wcol = (wid & 1) * 32;
    const int srow = tid >> 3, sseg = (tid & 7) * 8;
    f32x4 acc[2][2];
    #pragma unroll
    for (int i = 0; i < 2; ++i)
        #pragma unroll
        for (int j = 0; j < 2; ++j) acc[i][j] = (f32x4){0.f, 0.f, 0.f, 0.f};

    #pragma unroll 1
    for (int pass = 0; pass < 3; ++pass) {
        const unsigned short* Asrc = (pass < 2) ? Ahi : Alo;
        const unsigned short* Bsrc = (pass == 1) ? Blo : Bhi;
        for (int k0 = 0; k0 < 512; k0 += 64) {
            *reinterpret_cast<int4*>(&As[srow][sseg]) =
                *reinterpret_cast<const int4*>(&Asrc[(t0 + srow) * 512 + k0 + sseg]);
            *reinterpret_cast<int4*>(&As[srow + 32][sseg]) =
                *reinterpret_cast<const int4*>(&Asrc[(t0 + srow + 32) * 512 + k0 + sseg]);
            *reinterpret_cast<int4*>(&Bs[srow][sseg]) =
                *reinterpret_cast<const int4*>(&Bsrc[(j0 + srow) * 512 + k0 + sseg]);
            *reinterpret_cast<int4*>(&Bs[srow + 32][sseg]) =
                *reinterpret_cast<const int4*>(&Bsrc[(j0 + srow + 32) * 512 + k0 + sseg]);
            __syncthreads();
            #pragma unroll
            for (int kh = 0; kh < 2; ++kh) {
                const int kb = kh * 32 + (lane >> 4) * 8;
                bf16x8 a0 = *reinterpret_cast<const bf16x8*>(&As[wrow + (lane & 15)][kb]);
                bf16x8 a1 = *reinterpret_cast<const bf16x8*>(&As[wrow + 16 + (lane & 15)][kb]);
                bf16x8 b0 = *reinterpret_cast<const bf16x8*>(&Bs[wcol + (lane & 15)][kb]);
                bf16x8 b1 = *reinterpret_cast<const bf16x8*>(&Bs[wcol + 16 + (lane & 15)][kb]);
                acc[0][0] = __builtin_amdgcn_mfma_f32_16x16x32_bf16(a0, b0, acc[0][0], 0, 0, 0);
                acc[0][1] = __builtin_amdgcn_mfma_f32_16x16x32_bf16(a0, b1, acc[0][1], 0, 0, 0);
                acc[1][0] = __builtin_amdgcn_mfma_f32_16x16x32_bf16(a1, b0, acc[1][0], 0, 0, 0);
                acc[1][1] = __builtin_amdgcn_mfma_f32_16x16x32_bf16(a1, b1, acc[1][1], 0, 0, 0);
            }
            __syncthreads();
        }
    }
    #pragma unroll
    for (int i = 0; i < 2; ++i)
        #pragma unroll
        for (int j = 0; j < 2; ++j)
            #pragma unroll
            for (int r = 0; r < 4; ++r) {
                int row = wrow + i * 16 + (lane >> 4) * 4 + r;
                int col = wcol + j * 16 + (lane & 15);
                int t = t0 + row, n = j0 + col;
                Y[t * EMB + n] = acc[i][j][r] + bias[n];
            }
}

// ---------------------------------------------------------------------------
// Kernel 2: features. One block per (h,t); wave0 -> q, wave1 -> k.
// ---------------------------------------------------------------------------
__global__ __launch_bounds__(128) void k_features(
    const float* __restrict__ Qh, const float* __restrict__ Kh,
    const float* __restrict__ poly_proj, const float* __restrict__ omega,
    float* __restrict__ QF, float* __restrict__ KF)
{
    const int ht = blockIdx.x;          // h*T + t
    const int h = ht >> 10;
    const int wid = threadIdx.x >> 6, lane = threadIdx.x & 63;
    const float* Z = (wid ? Kh : Qh) + ht * HD;
    float z = Z[lane];
    float ss = z * z;
    #pragma unroll
    for (int off = 32; off; off >>= 1) ss += __shfl_xor(ss, off, 64);
    const float inv = 1.0f / fmaxf(sqrtf(ss), 1e-12f);
    __shared__ float zs[2][64];
    __shared__ float poly[2][32];
    __shared__ float prf[2][4];
    zs[wid][lane] = z * inv;
    __syncthreads();
    const float S_NODE = (float)(1.0 / 2.000001);  // matches numpy astype(f32)
    const float SQRT2S = sqrtf(2.0f * S_NODE);
    if (lane < 32) {
        float a = 0.0f;
        for (int d = 0; d < 64; ++d)
            a = fmaf(zs[wid][d], poly_proj[(h * 64 + d) * 32 + lane], a);
        poly[wid][lane] = a * a;
    } else if (lane < 36) {
        const int m = lane - 32;
        float a = 0.0f;
        for (int d = 0; d < 64; ++d)
            a = fmaf(zs[wid][d], omega[(h * 64 + d) * 4 + m], a);
        float arg = fminf(fmaxf(fmaf(a, SQRT2S, -S_NODE), -20.0f), 20.0f);
        prf[wid][m] = expf(arg) * 0.5f;   // / sqrt(M=4)
    }
    __syncthreads();
    float* dst = wid ? KF : QF;
    #pragma unroll
    for (int r = 0; r < 2; ++r) {
        int f = lane * 2 + r;
        dst[ht * FDIM + f] = poly[wid][f >> 2] * prf[wid][f & 3];
    }
}

// ---------------------------------------------------------------------------
// Kernel 3: per-chunk state sums  S_c[f][d] = sum_t kf[t][f]*v[t][d], z_c[f].
// ---------------------------------------------------------------------------
__global__ __launch_bounds__(256) void k_chunk_kv(
    const float* __restrict__ KF, const float* __restrict__ Vh,
    float* __restrict__ Sch, float* __restrict__ zch)
{
    const int b = blockIdx.x;
    const int h = b >> 4, c = b & 15;
    const int t0 = c * TC;
    __shared__ float Ks[16][128];   // [kk][f]
    __shared__ float Vs[16][68];    // [kk][d]
    const int tid = threadIdx.x;
    const int tr = tid >> 4, tc_ = tid & 15;
    float acc[8][4] = {};
    float zsum = 0.0f;
    for (int tt0 = 0; tt0 < TC; tt0 += 16) {
        #pragma unroll
        for (int l = 0; l < 2; ++l) {
            int j = tid + l * 256;
            int kk = j >> 5, f4 = (j & 31) << 2;
            *reinterpret_cast<float4*>(&Ks[kk][f4]) =
                *reinterpret_cast<const float4*>(&KF[((h << 10) + t0 + tt0 + kk) * FDIM + f4]);
        }
        {
            int kk = tid >> 4, d4 = (tid & 15) << 2;
            *reinterpret_cast<float4*>(&Vs[kk][d4]) =
                *reinterpret_cast<const float4*>(&Vh[((h << 10) + t0 + tt0 + kk) * HD + d4]);
        }
        __syncthreads();
        #pragma unroll
        for (int kk = 0; kk < 16; ++kk) {
            float4 a0 = *reinterpret_cast<const float4*>(&Ks[kk][tr * 8]);
            float4 a1 = *reinterpret_cast<const float4*>(&Ks[kk][tr * 8 + 4]);
            float4 b4 = *reinterpret_cast<const float4*>(&Vs[kk][tc_ * 4]);
            float a[8] = {a0.x, a0.y, a0.z, a0.w, a1.x, a1.y, a1.z, a1.w};
            float bb[4] = {b4.x, b4.y, b4.z, b4.w};
            #pragma unroll
            for (int i = 0; i < 8; ++i)
                #pragma unroll
                for (int j = 0; j < 4; ++j) acc[i][j] = fmaf(a[i], bb[j], acc[i][j]);
        }
        if (tid < FDIM) {
            #pragma unroll
            for (int kk = 0; kk < 16; ++kk) zsum += Ks[kk][tid];
        }
        __syncthreads();
    }
    float* S = Sch + (size_t)(h * NC + c) * FDIM * HD;
    #pragma unroll
    for (int i = 0; i < 8; ++i) {
        int f = tr * 8 + i;
        *reinterpret_cast<float4*>(&S[f * HD + tc_ * 4]) =
            make_float4(acc[i][0], acc[i][1], acc[i][2], acc[i][3]);
    }
    if (tid < FDIM) zch[(h * NC + c) * FDIM + tid] = zsum;
}

// ---------------------------------------------------------------------------
// Kernel 4: exclusive prefix over chunks, one thread per chain.
// ---------------------------------------------------------------------------
__global__ __launch_bounds__(256) void k_prefix(
    const float* __restrict__ Sch, const float* __restrict__ zch,
    float* __restrict__ Spre, float* __restrict__ zpre)
{
    const int h = blockIdx.x >> 5;
    const int e = ((blockIdx.x & 31) << 8) + threadIdx.x;   // 0..8191
    const size_t base = (size_t)h * NC * FDIM * HD + e;
    float vals[NC];
    #pragma unroll
    for (int c = 0; c < NC; ++c)
        vals[c] = Sch[base + (size_t)c * FDIM * HD];
    float run = 0.0f;
    #pragma unroll
    for (int c = 0; c < NC; ++c) {
        Spre[base + (size_t)c * FDIM * HD] = run;
        run += vals[c];
    }
    if ((blockIdx.x & 31) == 0 && threadIdx.x < FDIM) {
        const int zb = h * NC * FDIM + threadIdx.x;
        float zv[NC];
        #pragma unroll
        for (int c = 0; c < NC; ++c) zv[c] = zch[zb + c * FDIM];
        float zr = 0.0f;
        #pragma unroll
        for (int c = 0; c < NC; ++c) {
            zpre[zb + c * FDIM] = zr;
            zr += zv[c];
        }
    }
}

// ---------------------------------------------------------------------------
// Kernel 5: per-chunk output; epilogue writes attn as bf16 hi/lo.
// ---------------------------------------------------------------------------
__global__ __launch_bounds__(256) void k_attn_out(
    const float* __restrict__ QF, const float* __restrict__ KF,
    const float* __restrict__ Vh,
    const float* __restrict__ Spre, const float* __restrict__ zpre,
    unsigned short* __restrict__ AThi, unsigned short* __restrict__ ATlo)
{
    const int b = blockIdx.x;
    const int h = b >> 4, c = b & 15;
    const int t0 = c * TC;
    const int tid = threadIdx.x;
    const int tr = tid >> 4, tc_ = tid & 15;

    __shared__ float A[TC][68];
    __shared__ float Qs[16][68];   // [kk][t]  (transposed qf tile)
    __shared__ float Bs[16][68];   // kf tile in phase 1, V tile in phase 3
    __shared__ float Ss[16][68];   // Spre tile
    __shared__ float nrm[TC];
    __shared__ float zpre_s[FDIM];

    if (tid < FDIM) zpre_s[tid] = zpre[(h * NC + c) * FDIM + tid];

    float acc1[4][4] = {};  // A tile
    float acc2[4][4] = {};  // context
    float nint = 0.0f;

    for (int f0 = 0; f0 < FDIM; f0 += 16) {
        {
            int tl = tid >> 2, fq = (tid & 3) << 2;
            float4 qv = *reinterpret_cast<const float4*>(
                &QF[((h << 10) + t0 + tl) * FDIM + f0 + fq]);
            Qs[fq+0][tl] = qv.x; Qs[fq+1][tl] = qv.y; Qs[fq+2][tl] = qv.z; Qs[fq+3][tl] = qv.w;
            float4 kv4 = *reinterpret_cast<const float4*>(
                &KF[((h << 10) + t0 + tl) * FDIM + f0 + fq]);
            Bs[fq+0][tl] = kv4.x; Bs[fq+1][tl] = kv4.y; Bs[fq+2][tl] = kv4.z; Bs[fq+3][tl] = kv4.w;
            int kkS = tid >> 4, d4 = (tid & 15) << 2;
            *reinterpret_cast<float4*>(&Ss[kkS][d4]) = *reinterpret_cast<const float4*>(
                &Spre[((size_t)(h * NC + c) * FDIM + f0 + kkS) * HD + d4]);
        }
        __syncthreads();
        #pragma unroll
        for (int kk = 0; kk < 16; ++kk) {
            float4 a4 = *reinterpret_cast<const float4*>(&Qs[kk][tr * 4]);
            float4 k4 = *reinterpret_cast<const float4*>(&Bs[kk][tc_ * 4]);
            float4 s4 = *reinterpret_cast<const float4*>(&Ss[kk][tc_ * 4]);
            float a[4] = {a4.x, a4.y, a4.z, a4.w};
            float bk[4] = {k4.x, k4.y, k4.z, k4.w};
            float bs[4] = {s4.x, s4.y, s4.z, s4.w};
            #pragma unroll
            for (int i = 0; i < 4; ++i)
                #pragma unroll
                for (int j = 0; j < 4; ++j) {
                    acc1[i][j] = fmaf(a[i], bk[j], acc1[i][j]);
                    acc2[i][j] = fmaf(a[i], bs[j], acc2[i][j]);
                }
        }
        if (tid < TC) {
            #pragma unroll
            for (int kk = 0; kk < 16; ++kk)
                nint = fmaf(Qs[kk][tid], zpre_s[f0 + kk], nint);
        }
        __syncthreads();
    }

    float rs[4];
    #pragma unroll
    for (int i = 0; i < 4; ++i) {
        int tl = tr * 4 + i;
        rs[i] = 0.0f;
        #pragma unroll
        for (int j = 0; j < 4; ++j) {
            int tp = tc_ * 4 + j;
            float vA = (tp <= tl) ? acc1[i][j] : 0.0f;
            acc1[i][j] = vA;
            rs[i] += vA;
        }
        #pragma unroll
        for (int off = 1; off < 16; off <<= 1) rs[i] += __shfl_xor(rs[i], off, 64);
    }
    if (tc_ == 0) {
        #pragma unroll
        for (int i = 0; i < 4; ++i) nrm[tr * 4 + i] = rs[i];
    }
    #pragma unroll
    for (int i = 0; i < 4; ++i)
        *reinterpret_cast<float4*>(&A[tr * 4 + i][tc_ * 4]) =
            make_float4(acc1[i][0], acc1[i][1], acc1[i][2], acc1[i][3]);
    __syncthreads();

    for (int kk0 = 0; kk0 < TC; kk0 += 16) {
        {
            int kkV = tid >> 4, d4 = (tid & 15) << 2;
            *reinterpret_cast<float4*>(&Bs[kkV][d4]) = *reinterpret_cast<const float4*>(
                &Vh[((h << 10) + t0 + kk0 + kkV) * HD + d4]);
        }
        __syncthreads();
        #pragma unroll
        for (int kk = 0; kk < 16; ++kk) {
            float4 b4 = *reinterpret_cast<const float4*>(&Bs[kk][tc_ * 4]);
            float bb[4] = {b4.x, b4.y, b4.z, b4.w};
            #pragma unroll
            for (int i = 0; i < 4; ++i) {
                float a = A[tr * 4 + i][kk0 + kk];
                #pragma unroll
                for (int j = 0; j < 4; ++j) acc2[i][j] = fmaf(a, bb[j], acc2[i][j]);
            }
        }
        __syncthreads();
    }

    if (tid < TC) nrm[tid] = fmaxf(nrm[tid] + nint, 1e-6f);
    __syncthreads();

    #pragma unroll
    for (int i = 0; i < 4; ++i) {
        int tg = t0 + tr * 4 + i;
        float n = nrm[tr * 4 + i];
        float o[4] = {acc2[i][0] / n, acc2[i][1] / n, acc2[i][2] / n, acc2[i][3] / n};
        ushort4 h4, l4;
        h4.x = f2bf(o[0]); l4.x = f2bf(o[0] - bf2f(h4.x));
        h4.y = f2bf(o[1]); l4.y = f2bf(o[1] - bf2f(h4.y));
        h4.z = f2bf(o[2]); l4.z = f2bf(o[2] - bf2f(h4.z));
        h4.w = f2bf(o[3]); l4.w = f2bf(o[3] - bf2f(h4.w));
        int base = tg * EMB + h * HD + tc_ * 4;
        *reinterpret_cast<ushort4*>(&AThi[base]) = h4;
        *reinterpret_cast<ushort4*>(&ATlo[base]) = l4;
    }
}

// ---------------------------------------------------------------------------
// Workspace overlays (all producer->consumer orderings verified):
//   Xhi/Xlo  live in Sch's space  (dead before k_chunk_kv writes Sch)
//   Whi/Wlo  live in Spre's space (dead before k_prefix writes Spre)
//   AThi/ATlo live in q's space   (q dead after k_features)
//   Ohi/Olo  have their own space (needed first and last)
// Total ws: ~24.2 MB (< 25.3 MB footprint of the round-2 passing version).
// ---------------------------------------------------------------------------
extern "C" void kernel_launch(void* const* d_in, const int* in_sizes, int n_in,
                              void* d_out, int out_size, void* d_ws, size_t ws_size,
                              hipStream_t stream) {
    const float* x         = (const float*)d_in[0];
    const float* qkv_w     = (const float*)d_in[1];
    const float* qkv_b     = (const float*)d_in[2];
    const float* out_w     = (const float*)d_in[3];
    const float* out_b     = (const float*)d_in[4];
    const float* omega     = (const float*)d_in[5];
    const float* poly_proj = (const float*)d_in[6];
    float* out = (float*)d_out;

    float* ws   = (float*)d_ws;
    float* q    = ws;                           // [H][T][D] 524288
    float* k    = q    + NH * T_LEN * HD;       // 524288
    float* v    = k    + NH * T_LEN * HD;       // 524288
    float* qf   = v    + NH * T_LEN * HD;       // [H][T][F] 1048576
    float* kf   = qf   + NH * T_LEN * FDIM;     // 1048576
    float* Sch  = kf   + NH * T_LEN * FDIM;     // [H][NC][F][D] 1048576
    float* Spre = Sch  + NH * NC * FDIM * HD;   // 1048576
    float* zch  = Spre + NH * NC * FDIM * HD;   // 16384
    float* zpre = zch  + NH * NC * FDIM;        // 16384
    float* oxtr = zpre + NH * NC * FDIM;        // 262144 (Ohi/Olo)

    unsigned short* Xhi  = (unsigned short*)Sch;    // 524288 bf16 (in Sch)
    unsigned short* Xlo  = Xhi + 524288;            // 524288 bf16 (in Sch)
    unsigned short* Whi  = (unsigned short*)Spre;   // 786432 bf16 (in Spre)
    unsigned short* Wlo  = Whi + 786432;            // 786432 bf16 (in Spre)
    unsigned short* Ohi  = (unsigned short*)oxtr;   // 262144 bf16
    unsigned short* Olo  = Ohi + 262144;            // 262144 bf16
    unsigned short* AThi = (unsigned short*)q;      // 524288 bf16 (in q)
    unsigned short* ATlo = AThi + 524288;           // 524288 bf16 (in q+k? no: q only)

    k_cvt<<<1536, 256, 0, stream>>>(x, qkv_w, out_w, Xhi, Xlo, Whi, Wlo, Ohi, Olo);
    k_qkv_mfma<<<dim3(24, 16), 256, 0, stream>>>(Xhi, Xlo, Whi, Wlo, qkv_b, q, k, v);
    k_features<<<NH * T_LEN, 128, 0, stream>>>(q, k, poly_proj, omega, qf, kf);
    k_chunk_kv<<<NH * NC, 256, 0, stream>>>(kf, v, Sch, zch);
    k_prefix<<<NH * 32, 256, 0, stream>>>(Sch, zch, Spre, zpre);
    k_attn_out<<<NH * NC, 256, 0, stream>>>(qf, kf, v, Spre, zpre, AThi, ATlo);
    k_out_mfma<<<dim3(8, 16), 256, 0, stream>>>(AThi, ATlo, Ohi, Olo, out_b, out);
}